// Round 4
// baseline (43.742 us; speedup 1.0000x reference)
//
#include <hip/hip_runtime.h>
#include <hip/hip_bf16.h>

// out = (x + 2) * 3 / 2 == 1.5*x + 3.0  (fp32 elementwise, memory-bound)
// 4096*8192 = 33,554,432 elements = 8,388,608 float4's.
//
// R4: 4 independent float4 loads per thread (4x memory-level parallelism
// per wave) before 4 NT stores. NT stores retained from R3 (keep 128 MiB
// input L3-resident across graph replays). Coalesced: thread t in block b
// accesses base + k*256 for k=0..3.

typedef float f32x4 __attribute__((ext_vector_type(4)));

__device__ __forceinline__ f32x4 affine4(f32x4 v) {
    f32x4 r;
    r.x = fmaf(v.x, 1.5f, 3.0f);
    r.y = fmaf(v.y, 1.5f, 3.0f);
    r.z = fmaf(v.z, 1.5f, 3.0f);
    r.w = fmaf(v.w, 1.5f, 3.0f);
    return r;
}

__global__ void affine_f4x4_nt_kernel(const f32x4* __restrict__ in,
                                      f32x4* __restrict__ out,
                                      int n4) {
    int base = blockIdx.x * (blockDim.x * 4) + threadIdx.x;
    int i0 = base;
    int i1 = base + 256;
    int i2 = base + 512;
    int i3 = base + 768;
    // full blocks: all 4 in range (grid sized so only last block may straddle)
    if (i3 < n4) {
        f32x4 v0 = in[i0];
        f32x4 v1 = in[i1];
        f32x4 v2 = in[i2];
        f32x4 v3 = in[i3];
        __builtin_nontemporal_store(affine4(v0), &out[i0]);
        __builtin_nontemporal_store(affine4(v1), &out[i1]);
        __builtin_nontemporal_store(affine4(v2), &out[i2]);
        __builtin_nontemporal_store(affine4(v3), &out[i3]);
    } else {
        if (i0 < n4) __builtin_nontemporal_store(affine4(in[i0]), &out[i0]);
        if (i1 < n4) __builtin_nontemporal_store(affine4(in[i1]), &out[i1]);
        if (i2 < n4) __builtin_nontemporal_store(affine4(in[i2]), &out[i2]);
    }
}

__global__ void affine_tail_kernel(const float* __restrict__ in,
                                   float* __restrict__ out,
                                   int start, int n) {
    int i = start + blockIdx.x * blockDim.x + threadIdx.x;
    if (i < n) out[i] = fmaf(in[i], 1.5f, 3.0f);
}

extern "C" void kernel_launch(void* const* d_in, const int* in_sizes, int n_in,
                              void* d_out, int out_size, void* d_ws, size_t ws_size,
                              hipStream_t stream) {
    const float* in = (const float*)d_in[0];
    float* out = (float*)d_out;
    int n = in_sizes[0];

    int n4 = n >> 2;                 // float4 count
    const int block = 256;
    const int per_block = block * 4; // 4 float4 per thread
    int grid = (n4 + per_block - 1) / per_block;
    if (grid < 1) grid = 1;

    affine_f4x4_nt_kernel<<<grid, block, 0, stream>>>(
        (const f32x4*)in, (f32x4*)out, n4);

    int tail_start = n4 << 2;
    int tail = n - tail_start;
    if (tail > 0) {
        affine_tail_kernel<<<1, 64, 0, stream>>>(in, out, tail_start, n);
    }
}

// Round 5
// 42.391 us; speedup vs baseline: 1.0319x; 1.0319x over previous
//
#include <hip/hip_runtime.h>
#include <hip/hip_bf16.h>

// out = (x + 2) * 3 / 2 == 1.5*x + 3.0  (fp32 elementwise, memory-bound)
// 4096*8192 = 33,554,432 elements = 8,388,608 float4's.
//
// R5: revert to the R3 winner. One float4 per thread + non-temporal store.
// R4's 4x-MLP variant regressed (43.74 vs 42.53 us) -> fabric-bound, not
// latency-bound. 42.53 us = 6.31 TB/s on 268 MB = at the measured 6.29 TB/s
// D2D copy ceiling.

typedef float f32x4 __attribute__((ext_vector_type(4)));

__global__ void affine_f4_nt_kernel(const f32x4* __restrict__ in,
                                    f32x4* __restrict__ out,
                                    int n4) {
    int i = blockIdx.x * blockDim.x + threadIdx.x;
    if (i < n4) {
        f32x4 v = in[i];
        f32x4 r;
        r.x = fmaf(v.x, 1.5f, 3.0f);
        r.y = fmaf(v.y, 1.5f, 3.0f);
        r.z = fmaf(v.z, 1.5f, 3.0f);
        r.w = fmaf(v.w, 1.5f, 3.0f);
        __builtin_nontemporal_store(r, &out[i]);
    }
}

__global__ void affine_tail_kernel(const float* __restrict__ in,
                                   float* __restrict__ out,
                                   int start, int n) {
    int i = start + blockIdx.x * blockDim.x + threadIdx.x;
    if (i < n) out[i] = fmaf(in[i], 1.5f, 3.0f);
}

extern "C" void kernel_launch(void* const* d_in, const int* in_sizes, int n_in,
                              void* d_out, int out_size, void* d_ws, size_t ws_size,
                              hipStream_t stream) {
    const float* in = (const float*)d_in[0];
    float* out = (float*)d_out;
    int n = in_sizes[0];

    int n4 = n >> 2;  // float4 count
    const int block = 256;
    int grid = (n4 + block - 1) / block;   // one float4 per thread
    if (grid < 1) grid = 1;

    affine_f4_nt_kernel<<<grid, block, 0, stream>>>(
        (const f32x4*)in, (f32x4*)out, n4);

    int tail_start = n4 << 2;
    int tail = n - tail_start;
    if (tail > 0) {
        affine_tail_kernel<<<1, 64, 0, stream>>>(in, out, tail_start, n);
    }
}